// Round 3
// baseline (392.174 us; speedup 1.0000x reference)
//
#include <hip/hip_runtime.h>
#include <hip/hip_cooperative_groups.h>
#include <cfloat>
#include <math.h>

namespace cg = cooperative_groups;

#define B_ 4
#define L_ 1024
#define D_ 8
#define OUT_ 224
#define NPIX (B_ * 2 * D_ * OUT_ * OUT_)   // 3211264
#define NT4  (NPIX / 4)                    // 802816
#define TBL 128                            // float offset of per-(b,d) tables in ws
#define TSTR 896                           // per-(b,d): CL[224] SL[224] RV0[224] RV1[224]

#define NPLANE 32
#define PB 16                              // blocks per plane
#define NBLK (NPLANE * PB)                 // 512
#define NBIN 2048                          // coarse histogram bins
#define SLOTCAP 1024                       // per-block candidate slot (floats)
#define GCAP 8192                          // per-plane candidate cap in LDS
// unordered ranks: ordered k = 1024 + 2*r -> r1=51917 (ordered 104858), r2=51918 (ordered 104859)
#define R1U 51917u
#define R2U 51918u

// scratch layout in d_out (4-byte words); all dead before the output phase writes.
#define SC_PHIST 0u                                   // NBLK*NBIN partial hists (4 MB)
#define SC_PGAF  ((unsigned)NBLK * (unsigned)NBIN)    // NBLK*2 floats
#define SC_CNT   (SC_PGAF + (unsigned)NBLK * 2u)      // NBLK counts
#define SC_SLOT  (SC_CNT + (unsigned)NBLK)            // NBLK*SLOTCAP floats (2 MB)

__device__ __forceinline__ float clipnorm(float v, float lo, float inv2, int degen) {
    float xn = degen ? -1.0f : ((v - lo) * inv2 - 1.0f);
    return fminf(fmaxf(xn, -1.0f + 1e-6f), 1.0f - 1e-6f);
}

__device__ __forceinline__ float sort64(float val, int tid) {
#pragma unroll
    for (int k = 2; k <= 64; k <<= 1) {
        bool up = ((tid & k) == 0);
#pragma unroll
        for (int j = k >> 1; j > 0; j >>= 1) {
            float o = __shfl_xor(val, j);
            bool lower = ((tid & j) == 0);
            float mn = fminf(val, o), mx = fmaxf(val, o);
            val = (lower == up) ? mn : mx;
        }
    }
    return val;
}

// ===========================================================================
// Cooperative mega-kernel: hist -> (bracket+collect) -> select -> output.
// 512 blocks x 256 threads, 2 blocks/CU co-resident (LDS 45KB, 8 waves/CU).
// ===========================================================================
__global__ __launch_bounds__(256, 2) void k_fused(const float* __restrict__ x,
                                                  float* __restrict__ ws,
                                                  unsigned* __restrict__ scratch,
                                                  float4* __restrict__ out4) {
    // one flat LDS region, aliased per phase
    __shared__ __align__(16) float shm[11264];        // 44 KB
    __shared__ float red[16];
    __shared__ unsigned wsum[8];
    __shared__ unsigned sB1, sB2, sBase, scnt, sT1, sT2, sC1, sH1, uminb, umaxb;
    __shared__ float sv1, sv2;
    __shared__ unsigned cpre[17];
    __shared__ float sc3[3];

    float* S    = shm;                        // [1024]  phases 0-2
    float* CCa  = shm + 1024;                 // [1024]  phase 0
    float* SSN  = shm + 2048;                 // [1024]  phase 0
    unsigned* HIST = (unsigned*)(shm + 3072); // [2048]  phase 0
    float* STAGE = shm + 3072;                // [2048]  phase 2 (aliases HIST)
    float* CAND = shm;                        // [8192]  phase 3
    float* NBUF = shm + 8192;                 // [2048]  phase 3
    unsigned* H2 = (unsigned*)(shm + 10240);  // [1024]  phase 3
    float* T0   = shm;                        // [448]   phase 4

    cg::grid_group grid = cg::this_grid();

    const int tid  = threadIdx.x;
    const int lane = tid & 63;
    const int wave = tid >> 6;
    const int bid  = blockIdx.x;
    const int p    = bid >> 4;        // plane 0..31
    const int bip  = bid & 15;        // block-in-plane 0..15
    const int b    = p >> 3, d = p & 7;

    // ---------------- Phase 0: global minmax + hist + GAF partials + tables --
    float lo = FLT_MAX, hi = -FLT_MAX;
    {
        const float4* x4 = (const float4*)x;
        for (int i = tid; i < (B_ * L_ * D_) / 4; i += 256) {
            float4 q = x4[i];
            lo = fminf(fminf(fminf(lo, q.x), q.y), fminf(q.z, q.w));
            hi = fmaxf(fmaxf(fmaxf(hi, q.x), q.y), fmaxf(q.z, q.w));
        }
#pragma unroll
        for (int off = 32; off; off >>= 1) {
            lo = fminf(lo, __shfl_down(lo, off));
            hi = fmaxf(hi, __shfl_down(hi, off));
        }
        if (lane == 0) { red[wave] = lo; red[8 + wave] = hi; }
    }
    __syncthreads();
    const float glo = fminf(fminf(red[0], red[1]), fminf(red[2], red[3]));
    const float ghi = fmaxf(fmaxf(red[8], red[9]), fmaxf(red[10], red[11]));
    const float rng   = ghi - glo;
    const int   degen = rng < 1e-8f;
    const float inv2  = 2.0f / (rng + 1e-8f);
    const float scale = (float)(NBIN - 1) / fmaxf(rng, 1e-20f);

    // stage series + cos/sin tables; zero hist
    for (int i = tid; i < L_; i += 256) {
        float v = x[(b * L_ + i) * D_ + d];
        float c = clipnorm(v, glo, inv2, degen);
        S[i] = v; CCa[i] = c; SSN[i] = sqrtf(fmaxf(0.0f, 1.0f - c * c));
    }
    for (int i = tid; i < NBIN; i += 256) HIST[i] = 0u;
    __syncthreads();

    // register-cached columns: tid, tid+256, tid+512, tid+768
    float sj[4], cj[4], zj[4];
#pragma unroll
    for (int q = 0; q < 4; q++) {
        int j = tid + q * 256;
        sj[q] = S[j]; cj[q] = CCa[j]; zj[q] = SSN[j];
    }
    float gmn = FLT_MAX, gmx = -FLT_MAX;
#pragma unroll
    for (int q = 0; q < 4; q++) {             // diagonal GAF terms
        float g = cj[q] * cj[q] - zj[q] * zj[q];
        gmn = fminf(gmn, g); gmx = fmaxf(gmx, g);
    }

    // rows [bip*32, bip*32+32) plus mirror rows; pairs j>i only
    for (int rp = 0; rp < 64; ++rp) {
        int i = (rp < 32) ? (bip * 32 + rp) : (L_ - 1 - (bip * 32 + rp - 32));
        float siv = S[i], civ = CCa[i], ziv = SSN[i];
#pragma unroll
        for (int q = 0; q < 4; q++) {
            int j = tid + q * 256;
            if (j > i) {
                float dd = fabsf(siv - sj[q]);
                int bin = (int)(dd * scale);
                bin = min(bin, NBIN - 1);
                atomicAdd(&HIST[bin], 1u);
                float g = civ * cj[q] - ziv * zj[q];
                gmn = fminf(gmn, g); gmx = fmaxf(gmx, g);
            }
        }
    }
    __syncthreads();

    // flush partial hist (coalesced)
    {
        unsigned* ph = scratch + SC_PHIST + (unsigned)bid * NBIN;
        for (int i = tid; i < NBIN; i += 256) ph[i] = HIST[i];
    }
    // GAF partials -> scratch
#pragma unroll
    for (int off = 32; off; off >>= 1) {
        gmn = fminf(gmn, __shfl_down(gmn, off));
        gmx = fmaxf(gmx, __shfl_down(gmx, off));
    }
    if (lane == 0) { red[wave] = gmn; red[8 + wave] = gmx; }
    __syncthreads();
    if (tid == 0) {
        float* pg = (float*)scratch + SC_PGAF + bid * 2;
        pg[0] = fminf(fminf(red[0], red[1]), fminf(red[2], red[3]));
        pg[1] = fmaxf(fmaxf(red[8], red[9]), fmaxf(red[10], red[11]));
    }
    // axis tables for output phase (one block per plane)
    if (bip == 0) {
        const float scL = (float)L_ / (float)OUT_;
        float* basep = ws + TBL + p * TSTR;
        for (int o = tid; o < OUT_; o += 256) {
            float fx = (o + 0.5f) * scL - 0.5f;
            int x0 = (int)fx; float wx = fx - (float)x0;
            float q0 = x[(b * L_ + x0) * D_ + d];
            float q1 = x[(b * L_ + x0 + 1) * D_ + d];
            float c0 = clipnorm(q0, glo, inv2, degen), c1 = clipnorm(q1, glo, inv2, degen);
            float s0 = sqrtf(fmaxf(0.0f, 1.0f - c0 * c0)), s1 = sqrtf(fmaxf(0.0f, 1.0f - c1 * c1));
            basep[o]        = c0 + wx * (c1 - c0);   // CL
            basep[OUT_ + o] = s0 + wx * (s1 - s0);   // SL
            basep[448 + o]  = q0;                    // RV0
            basep[672 + o]  = q1;                    // RV1
        }
    }

    __threadfence();
    grid.sync();

    // ---------------- Phase 2: redundant bracket + candidate collect ---------
    unsigned B1, B2, base;
    {
        unsigned loc[8];
#pragma unroll
        for (int q = 0; q < 8; q++) loc[q] = 0u;
        const unsigned* ph = scratch + SC_PHIST + (unsigned)(p * PB) * NBIN;
        for (int k = 0; k < PB; k++) {
            const uint4* ph4 = (const uint4*)(ph + (unsigned)k * NBIN) + tid * 2;
            uint4 a = ph4[0], c4 = ph4[1];
            loc[0] += a.x; loc[1] += a.y; loc[2] += a.z; loc[3] += a.w;
            loc[4] += c4.x; loc[5] += c4.y; loc[6] += c4.z; loc[7] += c4.w;
        }
        unsigned tsum = 0u;
#pragma unroll
        for (int q = 0; q < 8; q++) tsum += loc[q];
        unsigned inc = tsum;
#pragma unroll
        for (int off = 1; off < 64; off <<= 1) {
            unsigned o = __shfl_up(inc, off);
            if (lane >= off) inc += o;
        }
        if (lane == 63) wsum[wave] = inc;
        __syncthreads();
        unsigned woff = 0u;
        for (int w2 = 0; w2 < 4; w2++) woff += (w2 < wave) ? wsum[w2] : 0u;
        unsigned run = woff + inc - tsum;
#pragma unroll
        for (int q = 0; q < 8; q++) {
            unsigned prev = run; run += loc[q];
            if (prev < R1U && run >= R1U) { sB1 = (unsigned)(tid * 8 + q); sBase = prev; }
            if (prev < R2U && run >= R2U) { sB2 = (unsigned)(tid * 8 + q); }
        }
        __syncthreads();
        B1 = sB1; B2 = sB2; base = sBase;
    }
    // float filter identical to int binning: floor(y)>=B1 <=> y>=B1; floor(y)<=B2 <=> y<B2+1
    const float fB1   = (float)B1;
    const float fB2p1 = (B2 >= (unsigned)(NBIN - 1)) ? FLT_MAX : (float)(B2 + 1u);

    if (tid == 0) scnt = 0u;
    __syncthreads();
    for (int rp = 0; rp < 64; ++rp) {
        int i = (rp < 32) ? (bip * 32 + rp) : (L_ - 1 - (bip * 32 + rp - 32));
        float siv = S[i];
#pragma unroll
        for (int q = 0; q < 4; q++) {
            int j = tid + q * 256;
            if (j > i) {
                float dd = fabsf(siv - sj[q]);
                float y = dd * scale;
                if (y >= fB1 && y < fB2p1) {
                    unsigned idx = atomicAdd(&scnt, 1u);
                    if (idx < (unsigned)SLOTCAP) STAGE[idx] = dd;
                }
            }
        }
    }
    __syncthreads();
    {
        unsigned bc = scnt; bc = (bc < (unsigned)SLOTCAP) ? bc : (unsigned)SLOTCAP;
        float* slot = (float*)scratch + SC_SLOT + (unsigned)bid * SLOTCAP;
        for (unsigned idx = tid; idx < bc; idx += 256) slot[idx] = STAGE[idx];
        if (tid == 0) scratch[SC_CNT + bid] = bc;
    }

    __threadfence();
    grid.sync();

    // ---------------- Phase 3: exact selection (one block per plane) ---------
    if (bip == 0) {
        if (tid == 0) {
            unsigned acc = 0u;
            for (int k = 0; k < PB; k++) {
                cpre[k] = acc;
                acc += scratch[SC_CNT + (unsigned)(p * PB + k)];
            }
            cpre[16] = acc;
        }
        __syncthreads();
        unsigned n = cpre[16]; n = (n < (unsigned)GCAP) ? n : (unsigned)GCAP;
        for (int k = 0; k < PB; k++) {
            unsigned off = cpre[k], ck = cpre[k + 1] - cpre[k];
            const float* slot = (const float*)scratch + SC_SLOT + (unsigned)(p * PB + k) * SLOTCAP;
            for (unsigned idx = tid; idx < ck; idx += 256) {
                unsigned dst = off + idx;
                if (dst < (unsigned)GCAP) CAND[dst] = slot[idx];
            }
        }
        __syncthreads();

        float* cur = CAND;
        float* nxt = NBUF;
        unsigned ncur = n;
        unsigned r1 = R1U - base;             // 1-indexed rank within candidates
        float vlo = (float)B1 / scale;
        float vhi = (float)(B2 + 1u) / scale;
        float v1 = 0.0f, v2 = 0.0f;
        bool done = false;

        for (int it = 0; it < 6 && !done; ++it) {
            if (tid == 0) scnt = 0u;
#pragma unroll
            for (int q = 0; q < 4; q++) H2[tid + q * 256] = 0u;
            __syncthreads();

            if (ncur <= 64u) {
                if (tid < 64) {
                    float val = ((unsigned)tid < ncur) ? cur[tid] : FLT_MAX;
                    val = sort64(val, tid);
                    float v1l = __shfl(val, (int)r1 - 1);
                    float v2l = __shfl(val, (int)r1);
                    if (tid == 0) { sv1 = v1l; sv2 = v2l; }
                }
                __syncthreads();
                v1 = sv1; v2 = sv2;
                done = true;
                break;
            }

            float sc2 = 1023.0f / fmaxf(vhi - vlo, 1e-30f);
            for (unsigned k = tid; k < ncur; k += 256) {
                int bb = (int)((cur[k] - vlo) * sc2);
                bb = max(0, min(bb, 1023));
                atomicAdd(&H2[bb], 1u);
            }
            __syncthreads();

            // scan 1024 bins with 256 threads: thread owns H2[4t..4t+4)
            unsigned l[4];
#pragma unroll
            for (int q = 0; q < 4; q++) l[q] = H2[4 * tid + q];
            unsigned tsum = l[0] + l[1] + l[2] + l[3];
            unsigned inc = tsum;
#pragma unroll
            for (int off = 1; off < 64; off <<= 1) {
                unsigned o = __shfl_up(inc, off);
                if (lane >= off) inc += o;
            }
            if (lane == 63) wsum[wave] = inc;
            __syncthreads();
            unsigned woff = 0u;
            for (int w2 = 0; w2 < 4; w2++) woff += (w2 < wave) ? wsum[w2] : 0u;
            unsigned prev = woff + inc - tsum;
#pragma unroll
            for (int q = 0; q < 4; q++) {
                unsigned nrun = prev + l[q];
                if (prev < r1 && nrun >= r1) { sT1 = 4u * tid + q; sC1 = prev; sH1 = l[q]; }
                if (prev < r1 + 1u && nrun >= r1 + 1u) { sT2 = 4u * tid + q; }
                prev = nrun;
            }
            __syncthreads();
            const unsigned t1 = sT1, t2 = sT2, c1 = sC1, h1 = sH1;

            if (t1 != t2) {
                if (tid == 0) { uminb = 0xFFFFFFFFu; umaxb = 0u; }
                __syncthreads();
                for (unsigned k = tid; k < ncur; k += 256) {
                    float val = cur[k];
                    int bb = (int)((val - vlo) * sc2);
                    bb = max(0, min(bb, 1023));
                    if (bb == (int)t1) atomicMax(&umaxb, __float_as_uint(val));
                    else if (bb > (int)t1) atomicMin(&uminb, __float_as_uint(val));
                }
                __syncthreads();
                v1 = __uint_as_float(umaxb);
                v2 = __uint_as_float(uminb);
                done = true;
                break;
            }

            if (h1 <= 64u) {
                for (unsigned k = tid; k < ncur; k += 256) {
                    float val = cur[k];
                    int bb = (int)((val - vlo) * sc2);
                    bb = max(0, min(bb, 1023));
                    if (bb == (int)t1) {
                        unsigned idx = atomicAdd(&scnt, 1u);
                        if (idx < 64u) nxt[idx] = val;
                    }
                }
                __syncthreads();
                unsigned cnt = (scnt < 64u) ? scnt : 64u;
                unsigned rr = r1 - c1;
                if (tid < 64) {
                    float val = ((unsigned)tid < cnt) ? nxt[tid] : FLT_MAX;
                    val = sort64(val, tid);
                    float v1l = __shfl(val, (int)rr - 1);
                    float v2l = __shfl(val, (int)rr);
                    if (tid == 0) { sv1 = v1l; sv2 = v2l; }
                }
                __syncthreads();
                v1 = sv1; v2 = sv2;
                done = true;
                break;
            }

            // big bin: compact and refine
            for (unsigned k = tid; k < ncur; k += 256) {
                float val = cur[k];
                int bb = (int)((val - vlo) * sc2);
                bb = max(0, min(bb, 1023));
                if (bb == (int)t1) {
                    unsigned idx = atomicAdd(&scnt, 1u);
                    if (idx < 2048u) nxt[idx] = val;
                }
            }
            __syncthreads();
            ncur = (scnt < 2048u) ? scnt : 2048u;
            r1 = r1 - c1;
            float nvlo = vlo + (float)t1 / sc2;
            float nvhi = vlo + (float)(t1 + 1u) / sc2;
            vlo = nvlo; vhi = nvhi;
            float* tmp = cur; cur = nxt; nxt = tmp;
            __syncthreads();
        }
        if (!done) { v1 = vlo; v2 = vhi; }    // pathological ties fallback

        if (tid < 16) {
            const float* pg = (const float*)scratch + SC_PGAF + (unsigned)(p * PB + tid) * 2u;
            float mn = pg[0], mx = pg[1];
#pragma unroll
            for (int off = 8; off; off >>= 1) {
                mn = fminf(mn, __shfl_down(mn, off));
                mx = fmaxf(mx, __shfl_down(mx, off));
            }
            if (tid == 0) {
                ws[2 + p * 3 + 0] = mn;
                ws[2 + p * 3 + 1] = mx;
                ws[2 + p * 3 + 2] = v1 + (v2 - v1) * 0.5f;
            }
        }
        __syncthreads();
    }

    __threadfence();
    grid.sync();

    // ---------------- Phase 4: output (k_out math, 8 blocks per image) -------
    {
        const int c = (bip < 8) ? d : (8 + d);
        const float* tb = ws + TBL + p * TSTR + ((bip < 8) ? 0 : 448);
        for (int i = tid; i < 448; i += 256) T0[i] = tb[i];
        if (tid == 0) {
            if (bip < 8) {
                float mn = ws[2 + p * 3 + 0];
                float mx = ws[2 + p * 3 + 1];
                float g = mx - mn;
                sc3[0] = mn;
                sc3[1] = (g < 1e-8f) ? 0.0f : 1.0f / (g + 1e-8f);
                sc3[2] = (g < 1e-8f) ? 1.0f : 0.0f;
            } else {
                sc3[0] = ws[2 + p * 3 + 2];
            }
        }
        __syncthreads();

        const int row0 = (bip & 7) * 28;
        const unsigned imgbase4 = (unsigned)(b * 16 + c) * 12544u;   // 50176/4

        for (int idx = tid; idx < 1568; idx += 256) {
            int col = idx % 56;
            int ox0 = col * 4;
            int oy  = row0 + idx / 56;
            float4 r;
            if (bip < 8) {
                float mn = sc3[0], ginv = sc3[1];
                bool gdeg = sc3[2] != 0.0f;
                float Cr = T0[oy], Sr = T0[OUT_ + oy];
                float4 Cc = *(const float4*)&T0[ox0];
                float4 Sc = *(const float4*)&T0[OUT_ + ox0];
                r.x = gdeg ? 0.0f : ((Cr * Cc.x - Sr * Sc.x) - mn) * ginv;
                r.y = gdeg ? 0.0f : ((Cr * Cc.y - Sr * Sc.y) - mn) * ginv;
                r.z = gdeg ? 0.0f : ((Cr * Cc.z - Sr * Sc.z) - mn) * ginv;
                r.w = gdeg ? 0.0f : ((Cr * Cc.w - Sr * Sc.w) - mn) * ginv;
            } else {
                float thr = sc3[0];
                const float scL = (float)L_ / (float)OUT_;
                float fy = (oy + 0.5f) * scL - 0.5f;
                int y0 = (int)fy; float wy = fy - (float)y0;
                float r0 = T0[oy], r1v = T0[OUT_ + oy];
                float4 q0 = *(const float4*)&T0[ox0];
                float4 q1 = *(const float4*)&T0[OUT_ + ox0];
                float qq0[4] = {q0.x, q0.y, q0.z, q0.w};
                float qq1[4] = {q1.x, q1.y, q1.z, q1.w};
                float res[4];
#pragma unroll
                for (int pq = 0; pq < 4; pq++) {
                    float fx = (ox0 + pq + 0.5f) * scL - 0.5f;
                    int x0i = (int)fx; float wx = fx - (float)x0i;
                    float v00 = (fabsf(r0 - qq0[pq]) <= thr) ? 1.0f : 0.0f;
                    float v01 = (fabsf(r0 - qq1[pq]) <= thr) ? 1.0f : 0.0f;
                    float v10 = (fabsf(r1v - qq0[pq]) <= thr) ? 1.0f : 0.0f;
                    float v11 = (fabsf(r1v - qq1[pq]) <= thr) ? 1.0f : 0.0f;
                    float top = v00 + wx * (v01 - v00);
                    float bot = v10 + wx * (v11 - v10);
                    res[pq] = top + wy * (bot - top);
                }
                r = make_float4(res[0], res[1], res[2], res[3]);
            }
            out4[imgbase4 + (unsigned)(oy * 56 + col)] = r;
        }
    }
}

// ===========================================================================
// Fallback path (verified round-2 kernels), used only if cooperative launch
// is unavailable.
// ===========================================================================
#define FCAP 8192
__global__ __launch_bounds__(256) void k_pairs(const float* __restrict__ x,
                                               float* __restrict__ ws,
                                               unsigned* __restrict__ scratch) {
    __shared__ float s[L_], cc[L_], ssn[L_];
    __shared__ unsigned hist[NBIN];
    __shared__ float red[16];

    const int tid  = threadIdx.x;
    const int lane = tid & 63;
    const int wave = tid >> 6;
    const int bid  = blockIdx.x;
    const int p    = bid >> 4;
    const int bip  = bid & 15;
    const int b    = p >> 3, d = p & 7;

    float lo = FLT_MAX, hi = -FLT_MAX;
    const float4* x4 = (const float4*)x;
    for (int i = tid; i < (B_ * L_ * D_) / 4; i += 256) {
        float4 q = x4[i];
        lo = fminf(fminf(fminf(lo, q.x), q.y), fminf(q.z, q.w));
        hi = fmaxf(fmaxf(fmaxf(hi, q.x), q.y), fmaxf(q.z, q.w));
    }
#pragma unroll
    for (int off = 32; off; off >>= 1) {
        lo = fminf(lo, __shfl_down(lo, off));
        hi = fmaxf(hi, __shfl_down(hi, off));
    }
    if (lane == 0) { red[wave] = lo; red[8 + wave] = hi; }
    __syncthreads();
    const float glo = fminf(fminf(red[0], red[1]), fminf(red[2], red[3]));
    const float ghi = fmaxf(fmaxf(red[8], red[9]), fmaxf(red[10], red[11]));
    const float rng   = ghi - glo;
    const int   degen = rng < 1e-8f;
    const float inv2  = 2.0f / (rng + 1e-8f);
    const float scale = (float)(NBIN - 1) / fmaxf(rng, 1e-20f);

    if (bid == 0 && tid == 0) { ws[0] = glo; ws[1] = ghi; }

    for (int i = tid; i < L_; i += 256) {
        float v = x[(b * L_ + i) * D_ + d];
        float c = clipnorm(v, glo, inv2, degen);
        s[i] = v; cc[i] = c; ssn[i] = sqrtf(fmaxf(0.0f, 1.0f - c * c));
    }
    for (int i = tid; i < NBIN; i += 256) hist[i] = 0u;
    __syncthreads();

    float sj[4], cj[4], zj[4];
#pragma unroll
    for (int q = 0; q < 4; q++) {
        int j = tid + q * 256;
        sj[q] = s[j]; cj[q] = cc[j]; zj[q] = ssn[j];
    }
    float gmn = FLT_MAX, gmx = -FLT_MAX;
#pragma unroll
    for (int q = 0; q < 4; q++) {
        float g = cj[q] * cj[q] - zj[q] * zj[q];
        gmn = fminf(gmn, g); gmx = fmaxf(gmx, g);
    }
    for (int rp = 0; rp < 64; ++rp) {
        int i = (rp < 32) ? (bip * 32 + rp) : (L_ - 1 - (bip * 32 + rp - 32));
        float siv = s[i], civ = cc[i], ziv = ssn[i];
#pragma unroll
        for (int q = 0; q < 4; q++) {
            int j = tid + q * 256;
            if (j > i) {
                float dd = fabsf(siv - sj[q]);
                int bin = (int)(dd * scale);
                bin = min(bin, NBIN - 1);
                atomicAdd(&hist[bin], 1u);
                float g = civ * cj[q] - ziv * zj[q];
                gmn = fminf(gmn, g); gmx = fmaxf(gmx, g);
            }
        }
    }
    __syncthreads();
    {
        unsigned* ph = scratch + SC_PHIST + (unsigned)bid * NBIN;
        for (int i = tid; i < NBIN; i += 256) ph[i] = hist[i];
    }
#pragma unroll
    for (int off = 32; off; off >>= 1) {
        gmn = fminf(gmn, __shfl_down(gmn, off));
        gmx = fmaxf(gmx, __shfl_down(gmx, off));
    }
    if (lane == 0) { red[wave] = gmn; red[8 + wave] = gmx; }
    __syncthreads();
    if (tid == 0) {
        float* pg = (float*)scratch + SC_PGAF + bid * 2;
        pg[0] = fminf(fminf(red[0], red[1]), fminf(red[2], red[3]));
        pg[1] = fmaxf(fmaxf(red[8], red[9]), fmaxf(red[10], red[11]));
    }
    if (bip == 0) {
        const float scL = (float)L_ / (float)OUT_;
        float* basep = ws + TBL + p * TSTR;
        for (int o = tid; o < OUT_; o += 256) {
            float fx = (o + 0.5f) * scL - 0.5f;
            int x0 = (int)fx; float wx = fx - (float)x0;
            float q0 = x[(b * L_ + x0) * D_ + d];
            float q1 = x[(b * L_ + x0 + 1) * D_ + d];
            float c0 = clipnorm(q0, glo, inv2, degen), c1 = clipnorm(q1, glo, inv2, degen);
            float s0 = sqrtf(fmaxf(0.0f, 1.0f - c0 * c0)), s1 = sqrtf(fmaxf(0.0f, 1.0f - c1 * c1));
            basep[o]        = c0 + wx * (c1 - c0);
            basep[OUT_ + o] = s0 + wx * (s1 - s0);
            basep[448 + o]  = q0;
            basep[672 + o]  = q1;
        }
    }
}

__global__ __launch_bounds__(1024) void k_quant(const float* __restrict__ x,
                                                float* __restrict__ ws,
                                                const unsigned* __restrict__ scratch) {
    __shared__ float s[L_];
    __shared__ float cand[FCAP];
    __shared__ float nbuf[2048];
    __shared__ unsigned h2[1024];
    __shared__ unsigned wsum[16], wsum2[16];
    __shared__ unsigned sB1, sB2, sBase, scnt, uminb, umaxb, sT1, sT2, sC1, sH1;
    __shared__ float sv1, sv2;

    const int tid  = threadIdx.x;
    const int lane = tid & 63;
    const int wave = tid >> 6;
    const int p    = blockIdx.x;
    const int b    = p >> 3, d = p & 7;

    const float glo = ws[0], ghi = ws[1];
    const float scale = (float)(NBIN - 1) / fmaxf(ghi - glo, 1e-20f);

    s[tid] = x[(b * L_ + tid) * D_ + d];
    if (tid == 0) scnt = 0u;

    unsigned loc0 = 0u, loc1 = 0u;
    const unsigned* ph = scratch + SC_PHIST + (unsigned)(p * PB) * NBIN;
    for (int k = 0; k < PB; k++) {
        loc0 += ph[k * NBIN + 2 * tid];
        loc1 += ph[k * NBIN + 2 * tid + 1];
    }
    unsigned tsum = loc0 + loc1;
    unsigned inc = tsum;
#pragma unroll
    for (int off = 1; off < 64; off <<= 1) {
        unsigned o = __shfl_up(inc, off);
        if (lane >= off) inc += o;
    }
    if (lane == 63) wsum[wave] = inc;
    __syncthreads();
    if (wave == 0 && lane < 16) {
        unsigned wv = wsum[lane];
#pragma unroll
        for (int off = 1; off < 16; off <<= 1) {
            unsigned o = __shfl_up(wv, off);
            if (lane >= off) wv += o;
        }
        wsum2[lane] = wv;
    }
    __syncthreads();
    {
        unsigned run = inc - tsum + ((wave > 0) ? wsum2[wave - 1] : 0u);
        unsigned prev = run; run += loc0;
        if (prev < R1U && run >= R1U) { sB1 = (unsigned)(2 * tid); sBase = prev; }
        if (prev < R2U && run >= R2U) { sB2 = (unsigned)(2 * tid); }
        prev = run; run += loc1;
        if (prev < R1U && run >= R1U) { sB1 = (unsigned)(2 * tid + 1); sBase = prev; }
        if (prev < R2U && run >= R2U) { sB2 = (unsigned)(2 * tid + 1); }
    }
    __syncthreads();
    const unsigned B1 = sB1, B2 = sB2, base = sBase;
    const float fB1   = (float)B1;
    const float fB2p1 = (B2 >= (unsigned)(NBIN - 1)) ? FLT_MAX : (float)(B2 + 1u);

    const float sv = s[tid];
    for (int o = 1; o <= 512; ++o) {
        if (o == 512 && tid >= 512) break;
        float dd = fabsf(sv - s[(tid + o) & 1023]);
        float y = dd * scale;
        if (y >= fB1 && y < fB2p1) {
            unsigned idx = atomicAdd(&scnt, 1u);
            if (idx < (unsigned)FCAP) cand[idx] = dd;
        }
    }
    __syncthreads();
    unsigned n = scnt;
    n = (n < (unsigned)FCAP) ? n : (unsigned)FCAP;

    float* cur = cand;
    float* nxt = nbuf;
    unsigned ncur = n;
    unsigned r1 = R1U - base;
    float vlo = (float)B1 / scale;
    float vhi = (float)(B2 + 1u) / scale;
    float v1 = 0.0f, v2 = 0.0f;
    bool done = false;

    for (int it = 0; it < 6 && !done; ++it) {
        if (tid == 0) scnt = 0u;
        h2[tid] = 0u;
        __syncthreads();

        if (ncur <= 64u) {
            if (tid < 64) {
                float val = ((unsigned)tid < ncur) ? cur[tid] : FLT_MAX;
                val = sort64(val, tid);
                float v1l = __shfl(val, (int)r1 - 1);
                float v2l = __shfl(val, (int)r1);
                if (tid == 0) { sv1 = v1l; sv2 = v2l; }
            }
            __syncthreads();
            v1 = sv1; v2 = sv2;
            done = true;
            break;
        }

        float sc2 = 1023.0f / fmaxf(vhi - vlo, 1e-30f);
        for (unsigned k = tid; k < ncur; k += 1024) {
            int bb = (int)((cur[k] - vlo) * sc2);
            bb = max(0, min(bb, 1023));
            atomicAdd(&h2[bb], 1u);
        }
        __syncthreads();

        unsigned hv = h2[tid];
        unsigned inc2 = hv;
#pragma unroll
        for (int off = 1; off < 64; off <<= 1) {
            unsigned o = __shfl_up(inc2, off);
            if (lane >= off) inc2 += o;
        }
        if (lane == 63) wsum[wave] = inc2;
        __syncthreads();
        if (wave == 0 && lane < 16) {
            unsigned wv = wsum[lane];
#pragma unroll
            for (int off = 1; off < 16; off <<= 1) {
                unsigned o = __shfl_up(wv, off);
                if (lane >= off) wv += o;
            }
            wsum2[lane] = wv;
        }
        __syncthreads();
        unsigned cum  = inc2 + ((wave > 0) ? wsum2[wave - 1] : 0u);
        unsigned cumb = cum - hv;
        unsigned r2 = r1 + 1u;
        if (cum >= r1 && cumb < r1) { sT1 = (unsigned)tid; sC1 = cumb; sH1 = hv; }
        if (cum >= r2 && cumb < r2) { sT2 = (unsigned)tid; }
        __syncthreads();
        const unsigned t1 = sT1, t2 = sT2, c1 = sC1, h1 = sH1;

        if (t1 != t2) {
            if (tid == 0) { uminb = 0xFFFFFFFFu; umaxb = 0u; }
            __syncthreads();
            for (unsigned k = tid; k < ncur; k += 1024) {
                float val = cur[k];
                int bb = (int)((val - vlo) * sc2);
                bb = max(0, min(bb, 1023));
                if (bb == (int)t1) atomicMax(&umaxb, __float_as_uint(val));
                else if (bb > (int)t1) atomicMin(&uminb, __float_as_uint(val));
            }
            __syncthreads();
            v1 = __uint_as_float(umaxb);
            v2 = __uint_as_float(uminb);
            done = true;
            break;
        }

        if (h1 <= 64u) {
            for (unsigned k = tid; k < ncur; k += 1024) {
                float val = cur[k];
                int bb = (int)((val - vlo) * sc2);
                bb = max(0, min(bb, 1023));
                if (bb == (int)t1) {
                    unsigned idx = atomicAdd(&scnt, 1u);
                    if (idx < 64u) nxt[idx] = val;
                }
            }
            __syncthreads();
            unsigned cnt = (scnt < 64u) ? scnt : 64u;
            unsigned rr = r1 - c1;
            if (tid < 64) {
                float val = ((unsigned)tid < cnt) ? nxt[tid] : FLT_MAX;
                val = sort64(val, tid);
                float v1l = __shfl(val, (int)rr - 1);
                float v2l = __shfl(val, (int)rr);
                if (tid == 0) { sv1 = v1l; sv2 = v2l; }
            }
            __syncthreads();
            v1 = sv1; v2 = sv2;
            done = true;
            break;
        }

        for (unsigned k = tid; k < ncur; k += 1024) {
            float val = cur[k];
            int bb = (int)((val - vlo) * sc2);
            bb = max(0, min(bb, 1023));
            if (bb == (int)t1) {
                unsigned idx = atomicAdd(&scnt, 1u);
                if (idx < 2048u) nxt[idx] = val;
            }
        }
        __syncthreads();
        ncur = (scnt < 2048u) ? scnt : 2048u;
        r1 = r1 - c1;
        float nvlo = vlo + (float)t1 / sc2;
        float nvhi = vlo + (float)(t1 + 1u) / sc2;
        vlo = nvlo; vhi = nvhi;
        float* tmp = cur; cur = nxt; nxt = tmp;
        __syncthreads();
    }
    if (!done) { v1 = vlo; v2 = vhi; }

    if (tid < 16) {
        const float* pg = (const float*)scratch + SC_PGAF + (unsigned)(p * PB + tid) * 2u;
        float mn = pg[0], mx = pg[1];
#pragma unroll
        for (int off = 8; off; off >>= 1) {
            mn = fminf(mn, __shfl_down(mn, off));
            mx = fmaxf(mx, __shfl_down(mx, off));
        }
        if (tid == 0) {
            ws[2 + p * 3 + 0] = mn;
            ws[2 + p * 3 + 1] = mx;
            ws[2 + p * 3 + 2] = v1 + (v2 - v1) * 0.5f;
        }
    }
}

__global__ __launch_bounds__(256) void k_out(const float* __restrict__ ws,
                                             float4* __restrict__ out4) {
    __shared__ __align__(16) float lds[448];
    __shared__ float sc[3];

    const int tid = threadIdx.x;
    int plane = blockIdx.x / 49;
    int c = plane & 15, b = plane >> 4, d = c & 7;

    const float* tb = ws + TBL + (b * 8 + d) * TSTR + ((c < 8) ? 0 : 448);
    for (int i = tid; i < 448; i += 256) lds[i] = tb[i];
    if (tid == 0) {
        if (c < 8) {
            float mn = ws[2 + (b * 8 + d) * 3 + 0];
            float mx = ws[2 + (b * 8 + d) * 3 + 1];
            float g = mx - mn;
            sc[0] = mn;
            sc[1] = (g < 1e-8f) ? 0.0f : 1.0f / (g + 1e-8f);
            sc[2] = (g < 1e-8f) ? 1.0f : 0.0f;
        } else {
            sc[0] = ws[2 + (b * 8 + d) * 3 + 2];
        }
    }
    __syncthreads();

    int tix = blockIdx.x * 256 + tid;
    int pix0 = tix << 2;
    int ox0 = pix0 % OUT_;
    int oy  = (pix0 / OUT_) % OUT_;

    float4 r;
    if (c < 8) {
        float mn = sc[0], ginv = sc[1];
        bool gdeg = sc[2] != 0.0f;
        float Cr = lds[oy], Sr = lds[OUT_ + oy];
        float4 Cc = *(const float4*)&lds[ox0];
        float4 Sc = *(const float4*)&lds[OUT_ + ox0];
        r.x = gdeg ? 0.0f : ((Cr * Cc.x - Sr * Sc.x) - mn) * ginv;
        r.y = gdeg ? 0.0f : ((Cr * Cc.y - Sr * Sc.y) - mn) * ginv;
        r.z = gdeg ? 0.0f : ((Cr * Cc.z - Sr * Sc.z) - mn) * ginv;
        r.w = gdeg ? 0.0f : ((Cr * Cc.w - Sr * Sc.w) - mn) * ginv;
    } else {
        float thr = sc[0];
        const float scale = (float)L_ / (float)OUT_;
        float fy = (oy + 0.5f) * scale - 0.5f;
        int y0 = (int)fy; float wy = fy - (float)y0;
        float r0 = lds[oy], r1 = lds[OUT_ + oy];
        float4 q0 = *(const float4*)&lds[ox0];
        float4 q1 = *(const float4*)&lds[OUT_ + ox0];
        float qq0[4] = {q0.x, q0.y, q0.z, q0.w};
        float qq1[4] = {q1.x, q1.y, q1.z, q1.w};
        float res[4];
#pragma unroll
        for (int pq = 0; pq < 4; pq++) {
            float fx = (ox0 + pq + 0.5f) * scale - 0.5f;
            int x0i = (int)fx; float wx = fx - (float)x0i;
            float v00 = (fabsf(r0 - qq0[pq]) <= thr) ? 1.0f : 0.0f;
            float v01 = (fabsf(r0 - qq1[pq]) <= thr) ? 1.0f : 0.0f;
            float v10 = (fabsf(r1 - qq0[pq]) <= thr) ? 1.0f : 0.0f;
            float v11 = (fabsf(r1 - qq1[pq]) <= thr) ? 1.0f : 0.0f;
            float top = v00 + wx * (v01 - v00);
            float bot = v10 + wx * (v11 - v10);
            res[pq] = top + wy * (bot - top);
        }
        r = make_float4(res[0], res[1], res[2], res[3]);
    }
    out4[tix] = r;
}

extern "C" void kernel_launch(void* const* d_in, const int* in_sizes, int n_in,
                              void* d_out, int out_size, void* d_ws, size_t ws_size,
                              hipStream_t stream) {
    const float* x = (const float*)d_in[0];
    float* ws = (float*)d_ws;
    unsigned* scratch = (unsigned*)d_out;   // dead before the output phase writes
    float4* out4 = (float4*)d_out;

    void* args[] = { (void*)&x, (void*)&ws, (void*)&scratch, (void*)&out4 };
    hipError_t err = hipLaunchCooperativeKernel((const void*)k_fused,
                                                dim3(NBLK), dim3(256),
                                                args, 0, stream);
    if (err != hipSuccess) {
        // fallback: verified 3-kernel path
        k_pairs<<<NBLK, 256, 0, stream>>>(x, ws, scratch);
        k_quant<<<NPLANE, 1024, 0, stream>>>(x, ws, scratch);
        k_out<<<NT4 / 256, 256, 0, stream>>>(ws, out4);
    }
}

// Round 4
// 131.595 us; speedup vs baseline: 2.9802x; 2.9802x over previous
//
#include <hip/hip_runtime.h>
#include <cfloat>
#include <math.h>

#define B_ 4
#define L_ 1024
#define D_ 8
#define OUT_ 224
#define NPIX (B_ * 2 * D_ * OUT_ * OUT_)   // 3211264
#define NT4  (NPIX / 4)                    // 802816 = 3136 * 256 exactly
#define TBL 128                            // float offset of per-(b,d) tables in ws
#define TSTR 896                           // per-(b,d): CL[224] SL[224] RV0[224] RV1[224]

#define NPLANE 32
#define PB 16                              // blocks per plane in pair-sweep kernels
#define NBLK (NPLANE * PB)                 // 512
#define NBIN 2048                          // coarse histogram bins
#define SLOTCAP 1024                       // per-block candidate slot (floats)
#define GCAP 8192                          // per-plane candidate cap in LDS
// unordered ranks: ordered k = 1024 + 2*r -> r1=51917 (ordered 104858), r2=51918 (ordered 104859)
#define R1U 51917u
#define R2U 51918u

// scratch layout in d_out (4-byte words); all dead before k_out overwrites d_out.
#define SC_PHIST 0u                                   // NBLK*NBIN partial hists (4 MB)
#define SC_PGAF  ((unsigned)NBLK * (unsigned)NBIN)    // NBLK*2 floats
#define SC_CNT   (SC_PGAF + (unsigned)NBLK * 2u)      // NBLK counts
#define SC_SLOT  (SC_CNT + (unsigned)NBLK)            // NBLK*SLOTCAP floats (2 MB)

__device__ __forceinline__ float clipnorm(float v, float lo, float inv2, int degen) {
    float xn = degen ? -1.0f : ((v - lo) * inv2 - 1.0f);
    return fminf(fmaxf(xn, -1.0f + 1e-6f), 1.0f - 1e-6f);
}

__device__ __forceinline__ float sort64(float val, int tid) {
#pragma unroll
    for (int k = 2; k <= 64; k <<= 1) {
        bool up = ((tid & k) == 0);
#pragma unroll
        for (int j = k >> 1; j > 0; j >>= 1) {
            float o = __shfl_xor(val, j);
            bool lower = ((tid & j) == 0);
            float mn = fminf(val, o), mx = fmaxf(val, o);
            val = (lower == up) ? mn : mx;
        }
    }
    return val;
}

// ---------------------------------------------------------------------------
// K1: per-plane all-pairs sweep -> partial hist + GAF partials + axis tables.
// 512 blocks x 256 threads. (Verified green in R2/R3.)
// ---------------------------------------------------------------------------
__global__ __launch_bounds__(256) void k_pairs(const float* __restrict__ x,
                                               float* __restrict__ ws,
                                               unsigned* __restrict__ scratch) {
    __shared__ float s[L_], cc[L_], ssn[L_];
    __shared__ unsigned hist[NBIN];
    __shared__ float red[16];

    const int tid  = threadIdx.x;
    const int lane = tid & 63;
    const int wave = tid >> 6;
    const int bid  = blockIdx.x;
    const int p    = bid >> 4;        // plane 0..31
    const int bip  = bid & 15;        // block-in-plane 0..15
    const int b    = p >> 3, d = p & 7;

    // global min/max over all of x (identical traversal in every block)
    float lo = FLT_MAX, hi = -FLT_MAX;
    const float4* x4 = (const float4*)x;
    for (int i = tid; i < (B_ * L_ * D_) / 4; i += 256) {
        float4 q = x4[i];
        lo = fminf(fminf(fminf(lo, q.x), q.y), fminf(q.z, q.w));
        hi = fmaxf(fmaxf(fmaxf(hi, q.x), q.y), fmaxf(q.z, q.w));
    }
#pragma unroll
    for (int off = 32; off; off >>= 1) {
        lo = fminf(lo, __shfl_down(lo, off));
        hi = fmaxf(hi, __shfl_down(hi, off));
    }
    if (lane == 0) { red[wave] = lo; red[8 + wave] = hi; }
    __syncthreads();
    const float glo = fminf(fminf(red[0], red[1]), fminf(red[2], red[3]));
    const float ghi = fmaxf(fmaxf(red[8], red[9]), fmaxf(red[10], red[11]));
    const float rng   = ghi - glo;
    const int   degen = rng < 1e-8f;
    const float inv2  = 2.0f / (rng + 1e-8f);
    const float scale = (float)(NBIN - 1) / fmaxf(rng, 1e-20f);

    if (bid == 0 && tid == 0) { ws[0] = glo; ws[1] = ghi; }

    // stage series + cos/sin tables; zero hist
    for (int i = tid; i < L_; i += 256) {
        float v = x[(b * L_ + i) * D_ + d];
        float c = clipnorm(v, glo, inv2, degen);
        s[i] = v; cc[i] = c; ssn[i] = sqrtf(fmaxf(0.0f, 1.0f - c * c));
    }
    for (int i = tid; i < NBIN; i += 256) hist[i] = 0u;
    __syncthreads();

    // register-cached columns: tid, tid+256, tid+512, tid+768
    float sj[4], cj[4], zj[4];
#pragma unroll
    for (int q = 0; q < 4; q++) {
        int j = tid + q * 256;
        sj[q] = s[j]; cj[q] = cc[j]; zj[q] = ssn[j];
    }
    float gmn = FLT_MAX, gmx = -FLT_MAX;
#pragma unroll
    for (int q = 0; q < 4; q++) {         // diagonal GAF terms
        float g = cj[q] * cj[q] - zj[q] * zj[q];
        gmn = fminf(gmn, g); gmx = fmaxf(gmx, g);
    }

    // rows [bip*32, bip*32+32) plus mirror rows; pairs j>i only
    for (int rp = 0; rp < 64; ++rp) {
        int i = (rp < 32) ? (bip * 32 + rp) : (L_ - 1 - (bip * 32 + rp - 32));
        float siv = s[i], civ = cc[i], ziv = ssn[i];
#pragma unroll
        for (int q = 0; q < 4; q++) {
            int j = tid + q * 256;
            if (j > i) {
                float dd = fabsf(siv - sj[q]);
                int bin = (int)(dd * scale);
                bin = min(bin, NBIN - 1);
                atomicAdd(&hist[bin], 1u);
                float g = civ * cj[q] - ziv * zj[q];
                gmn = fminf(gmn, g); gmx = fmaxf(gmx, g);
            }
        }
    }
    __syncthreads();

    // flush partial hist (coalesced)
    {
        unsigned* ph = scratch + SC_PHIST + (unsigned)bid * NBIN;
        for (int i = tid; i < NBIN; i += 256) ph[i] = hist[i];
    }
    // GAF partials -> scratch
#pragma unroll
    for (int off = 32; off; off >>= 1) {
        gmn = fminf(gmn, __shfl_down(gmn, off));
        gmx = fmaxf(gmx, __shfl_down(gmx, off));
    }
    if (lane == 0) { red[wave] = gmn; red[8 + wave] = gmx; }
    __syncthreads();
    if (tid == 0) {
        float* pg = (float*)scratch + SC_PGAF + bid * 2;
        pg[0] = fminf(fminf(red[0], red[1]), fminf(red[2], red[3]));
        pg[1] = fmaxf(fmaxf(red[8], red[9]), fmaxf(red[10], red[11]));
    }
    // axis tables for k_out (one block per plane)
    if (bip == 0) {
        const float scL = (float)L_ / (float)OUT_;
        float* basep = ws + TBL + p * TSTR;
        for (int o = tid; o < OUT_; o += 256) {
            float fx = (o + 0.5f) * scL - 0.5f;
            int x0 = (int)fx; float wx = fx - (float)x0;
            float q0 = x[(b * L_ + x0) * D_ + d];
            float q1 = x[(b * L_ + x0 + 1) * D_ + d];
            float c0 = clipnorm(q0, glo, inv2, degen), c1 = clipnorm(q1, glo, inv2, degen);
            float s0 = sqrtf(fmaxf(0.0f, 1.0f - c0 * c0)), s1 = sqrtf(fmaxf(0.0f, 1.0f - c1 * c1));
            basep[o]        = c0 + wx * (c1 - c0);   // CL
            basep[OUT_ + o] = s0 + wx * (s1 - s0);   // SL
            basep[448 + o]  = q0;                    // RV0
            basep[672 + o]  = q1;                    // RV1
        }
    }
}

// ---------------------------------------------------------------------------
// K2: redundant per-block bracket from partial hists + candidate collect into
// private per-block global slots. 512 blocks x 256 threads. No global atomics.
// (R3 phase-2 code + a restage of the plane series.)
// ---------------------------------------------------------------------------
__global__ __launch_bounds__(256) void k_collect(const float* __restrict__ x,
                                                 const float* __restrict__ ws,
                                                 unsigned* __restrict__ scratch) {
    __shared__ float s[L_];
    __shared__ float stage[SLOTCAP];
    __shared__ unsigned wsum[4];
    __shared__ unsigned sB1, sB2, sBase, scnt;

    const int tid  = threadIdx.x;
    const int lane = tid & 63;
    const int wave = tid >> 6;
    const int bid  = blockIdx.x;
    const int p    = bid >> 4;
    const int bip  = bid & 15;
    const int b    = p >> 3, d = p & 7;

    const float glo = ws[0], ghi = ws[1];
    const float scale = (float)(NBIN - 1) / fmaxf(ghi - glo, 1e-20f);

    // restage series (L2-hot)
    for (int i = tid; i < L_; i += 256) s[i] = x[(b * L_ + i) * D_ + d];
    if (tid == 0) scnt = 0u;

    // reduce this plane's 16 partial hists; thread owns bins [8t, 8t+8)
    unsigned B1, B2, base;
    {
        unsigned loc[8];
#pragma unroll
        for (int q = 0; q < 8; q++) loc[q] = 0u;
        const unsigned* ph = scratch + SC_PHIST + (unsigned)(p * PB) * NBIN;
        for (int k = 0; k < PB; k++) {
            const uint4* ph4 = (const uint4*)(ph + (unsigned)k * NBIN) + tid * 2;
            uint4 a = ph4[0], c4 = ph4[1];
            loc[0] += a.x; loc[1] += a.y; loc[2] += a.z; loc[3] += a.w;
            loc[4] += c4.x; loc[5] += c4.y; loc[6] += c4.z; loc[7] += c4.w;
        }
        unsigned tsum = 0u;
#pragma unroll
        for (int q = 0; q < 8; q++) tsum += loc[q];
        unsigned inc = tsum;
#pragma unroll
        for (int off = 1; off < 64; off <<= 1) {
            unsigned o = __shfl_up(inc, off);
            if (lane >= off) inc += o;
        }
        if (lane == 63) wsum[wave] = inc;
        __syncthreads();
        unsigned woff = 0u;
        for (int w2 = 0; w2 < 4; w2++) woff += (w2 < wave) ? wsum[w2] : 0u;
        unsigned run = woff + inc - tsum;
#pragma unroll
        for (int q = 0; q < 8; q++) {
            unsigned prev = run; run += loc[q];
            if (prev < R1U && run >= R1U) { sB1 = (unsigned)(tid * 8 + q); sBase = prev; }
            if (prev < R2U && run >= R2U) { sB2 = (unsigned)(tid * 8 + q); }
        }
        __syncthreads();
        B1 = sB1; B2 = sB2; base = sBase;
        (void)base;
    }
    // float filter identical to int binning: floor(y)>=B1 <=> y>=B1; floor(y)<=B2 <=> y<B2+1
    const float fB1   = (float)B1;
    const float fB2p1 = (B2 >= (unsigned)(NBIN - 1)) ? FLT_MAX : (float)(B2 + 1u);

    // register columns
    float sj[4];
#pragma unroll
    for (int q = 0; q < 4; q++) sj[q] = s[tid + q * 256];

    for (int rp = 0; rp < 64; ++rp) {
        int i = (rp < 32) ? (bip * 32 + rp) : (L_ - 1 - (bip * 32 + rp - 32));
        float siv = s[i];
#pragma unroll
        for (int q = 0; q < 4; q++) {
            int j = tid + q * 256;
            if (j > i) {
                float dd = fabsf(siv - sj[q]);
                float y = dd * scale;
                if (y >= fB1 && y < fB2p1) {
                    unsigned idx = atomicAdd(&scnt, 1u);
                    if (idx < (unsigned)SLOTCAP) stage[idx] = dd;
                }
            }
        }
    }
    __syncthreads();
    {
        unsigned bc = scnt; bc = (bc < (unsigned)SLOTCAP) ? bc : (unsigned)SLOTCAP;
        float* slot = (float*)scratch + SC_SLOT + (unsigned)bid * SLOTCAP;
        for (unsigned idx = tid; idx < bc; idx += 256) slot[idx] = stage[idx];
        if (tid == 0) scratch[SC_CNT + bid] = bc;
    }
}

// ---------------------------------------------------------------------------
// K3: per plane, gather candidates + exact selection of ranks r1/r1+1; write
// thr + GAF min/max. 32 blocks x 256 threads. (R3 phase-3 code.)
// ---------------------------------------------------------------------------
__global__ __launch_bounds__(256) void k_select(float* __restrict__ ws,
                                                const unsigned* __restrict__ scratch) {
    __shared__ float cand[GCAP];       // 32 KB
    __shared__ float nbuf[2048];       // 8 KB
    __shared__ unsigned h2[1024];      // 4 KB
    __shared__ unsigned wsum[4];
    __shared__ unsigned sB1, sB2, sBase, scnt, sT1, sT2, sC1, sH1, uminb, umaxb;
    __shared__ float sv1, sv2;
    __shared__ unsigned cpre[17];

    const int tid  = threadIdx.x;
    const int lane = tid & 63;
    const int wave = tid >> 6;
    const int p    = blockIdx.x;

    const float glo = ws[0], ghi = ws[1];
    const float scale = (float)(NBIN - 1) / fmaxf(ghi - glo, 1e-20f);

    // rebuild bracket (B1,B2,base) from the plane hist: thread owns [8t,8t+8)
    {
        unsigned loc[8];
#pragma unroll
        for (int q = 0; q < 8; q++) loc[q] = 0u;
        const unsigned* ph = scratch + SC_PHIST + (unsigned)(p * PB) * NBIN;
        for (int k = 0; k < PB; k++) {
            const uint4* ph4 = (const uint4*)(ph + (unsigned)k * NBIN) + tid * 2;
            uint4 a = ph4[0], c4 = ph4[1];
            loc[0] += a.x; loc[1] += a.y; loc[2] += a.z; loc[3] += a.w;
            loc[4] += c4.x; loc[5] += c4.y; loc[6] += c4.z; loc[7] += c4.w;
        }
        unsigned tsum = 0u;
#pragma unroll
        for (int q = 0; q < 8; q++) tsum += loc[q];
        unsigned inc = tsum;
#pragma unroll
        for (int off = 1; off < 64; off <<= 1) {
            unsigned o = __shfl_up(inc, off);
            if (lane >= off) inc += o;
        }
        if (lane == 63) wsum[wave] = inc;
        __syncthreads();
        unsigned woff = 0u;
        for (int w2 = 0; w2 < 4; w2++) woff += (w2 < wave) ? wsum[w2] : 0u;
        unsigned run = woff + inc - tsum;
#pragma unroll
        for (int q = 0; q < 8; q++) {
            unsigned prev = run; run += loc[q];
            if (prev < R1U && run >= R1U) { sB1 = (unsigned)(tid * 8 + q); sBase = prev; }
            if (prev < R2U && run >= R2U) { sB2 = (unsigned)(tid * 8 + q); }
        }
    }
    // parallel prefix of the plane's 16 slot counts (wave 0)
    if (wave == 0) {
        unsigned c = (lane < PB) ? scratch[SC_CNT + (unsigned)(p * PB + lane)] : 0u;
        unsigned incc = c;
#pragma unroll
        for (int off = 1; off < 16; off <<= 1) {
            unsigned o = __shfl_up(incc, off);
            if ((lane & 15) >= off) incc += o;
        }
        if (lane < PB) { cpre[lane] = incc - c; if (lane == PB - 1) cpre[16] = incc; }
    }
    __syncthreads();
    const unsigned B1 = sB1, B2 = sB2, base = sBase;

    unsigned n = cpre[16]; n = (n < (unsigned)GCAP) ? n : (unsigned)GCAP;
    for (int k = 0; k < PB; k++) {
        unsigned off = cpre[k], ck = cpre[k + 1 == PB ? 16 : k + 1] - cpre[k];
        if (k + 1 < PB) ck = cpre[k + 1] - cpre[k];
        const float* slot = (const float*)scratch + SC_SLOT + (unsigned)(p * PB + k) * SLOTCAP;
        for (unsigned idx = tid; idx < ck; idx += 256) {
            unsigned dst = off + idx;
            if (dst < (unsigned)GCAP) cand[dst] = slot[idx];
        }
    }
    __syncthreads();

    float* cur = cand;
    float* nxt = nbuf;
    unsigned ncur = n;
    unsigned r1 = R1U - base;             // 1-indexed rank within candidates
    float vlo = (float)B1 / scale;
    float vhi = (float)(B2 + 1u) / scale;
    float v1 = 0.0f, v2 = 0.0f;
    bool done = false;

    for (int it = 0; it < 6 && !done; ++it) {
        if (tid == 0) scnt = 0u;
#pragma unroll
        for (int q = 0; q < 4; q++) h2[tid + q * 256] = 0u;
        __syncthreads();

        if (ncur <= 64u) {
            if (tid < 64) {
                float val = ((unsigned)tid < ncur) ? cur[tid] : FLT_MAX;
                val = sort64(val, tid);
                float v1l = __shfl(val, (int)r1 - 1);
                float v2l = __shfl(val, (int)r1);
                if (tid == 0) { sv1 = v1l; sv2 = v2l; }
            }
            __syncthreads();
            v1 = sv1; v2 = sv2;
            done = true;
            break;
        }

        float sc2 = 1023.0f / fmaxf(vhi - vlo, 1e-30f);
        for (unsigned k = tid; k < ncur; k += 256) {
            int bb = (int)((cur[k] - vlo) * sc2);
            bb = max(0, min(bb, 1023));
            atomicAdd(&h2[bb], 1u);
        }
        __syncthreads();

        // scan 1024 bins with 256 threads: thread owns h2[4t..4t+4)
        unsigned l[4];
#pragma unroll
        for (int q = 0; q < 4; q++) l[q] = h2[4 * tid + q];
        unsigned tsum = l[0] + l[1] + l[2] + l[3];
        unsigned inc = tsum;
#pragma unroll
        for (int off = 1; off < 64; off <<= 1) {
            unsigned o = __shfl_up(inc, off);
            if (lane >= off) inc += o;
        }
        if (lane == 63) wsum[wave] = inc;
        __syncthreads();
        unsigned woff = 0u;
        for (int w2 = 0; w2 < 4; w2++) woff += (w2 < wave) ? wsum[w2] : 0u;
        unsigned prev = woff + inc - tsum;
#pragma unroll
        for (int q = 0; q < 4; q++) {
            unsigned nrun = prev + l[q];
            if (prev < r1 && nrun >= r1) { sT1 = 4u * tid + q; sC1 = prev; sH1 = l[q]; }
            if (prev < r1 + 1u && nrun >= r1 + 1u) { sT2 = 4u * tid + q; }
            prev = nrun;
        }
        __syncthreads();
        const unsigned t1 = sT1, t2 = sT2, c1 = sC1, h1 = sH1;

        if (t1 != t2) {
            if (tid == 0) { uminb = 0xFFFFFFFFu; umaxb = 0u; }
            __syncthreads();
            for (unsigned k = tid; k < ncur; k += 256) {
                float val = cur[k];
                int bb = (int)((val - vlo) * sc2);
                bb = max(0, min(bb, 1023));
                if (bb == (int)t1) atomicMax(&umaxb, __float_as_uint(val));
                else if (bb > (int)t1) atomicMin(&uminb, __float_as_uint(val));
            }
            __syncthreads();
            v1 = __uint_as_float(umaxb);
            v2 = __uint_as_float(uminb);
            done = true;
            break;
        }

        if (h1 <= 64u) {
            for (unsigned k = tid; k < ncur; k += 256) {
                float val = cur[k];
                int bb = (int)((val - vlo) * sc2);
                bb = max(0, min(bb, 1023));
                if (bb == (int)t1) {
                    unsigned idx = atomicAdd(&scnt, 1u);
                    if (idx < 64u) nxt[idx] = val;
                }
            }
            __syncthreads();
            unsigned cnt = (scnt < 64u) ? scnt : 64u;
            unsigned rr = r1 - c1;
            if (tid < 64) {
                float val = ((unsigned)tid < cnt) ? nxt[tid] : FLT_MAX;
                val = sort64(val, tid);
                float v1l = __shfl(val, (int)rr - 1);
                float v2l = __shfl(val, (int)rr);
                if (tid == 0) { sv1 = v1l; sv2 = v2l; }
            }
            __syncthreads();
            v1 = sv1; v2 = sv2;
            done = true;
            break;
        }

        // big bin: compact and refine
        for (unsigned k = tid; k < ncur; k += 256) {
            float val = cur[k];
            int bb = (int)((val - vlo) * sc2);
            bb = max(0, min(bb, 1023));
            if (bb == (int)t1) {
                unsigned idx = atomicAdd(&scnt, 1u);
                if (idx < 2048u) nxt[idx] = val;
            }
        }
        __syncthreads();
        ncur = (scnt < 2048u) ? scnt : 2048u;
        r1 = r1 - c1;
        float nvlo = vlo + (float)t1 / sc2;
        float nvhi = vlo + (float)(t1 + 1u) / sc2;
        vlo = nvlo; vhi = nvhi;
        float* tmp = cur; cur = nxt; nxt = tmp;
        __syncthreads();
    }
    if (!done) { v1 = vlo; v2 = vhi; }    // pathological ties fallback

    if (tid < 16) {
        const float* pg = (const float*)scratch + SC_PGAF + (unsigned)(p * PB + tid) * 2u;
        float mn = pg[0], mx = pg[1];
#pragma unroll
        for (int off = 8; off; off >>= 1) {
            mn = fminf(mn, __shfl_down(mn, off));
            mx = fmaxf(mx, __shfl_down(mx, off));
        }
        if (tid == 0) {
            ws[2 + p * 3 + 0] = mn;
            ws[2 + p * 3 + 1] = mx;
            ws[2 + p * 3 + 2] = v1 + (v2 - v1) * 0.5f;
        }
    }
}

// ---------------------------------------------------------------------------
// K4: output kernel — verbatim green. Overwrites all of d_out (incl. scratch).
// ---------------------------------------------------------------------------
__global__ __launch_bounds__(256) void k_out(const float* __restrict__ ws,
                                             float4* __restrict__ out4) {
    __shared__ __align__(16) float lds[448];
    __shared__ float sc[3];

    const int tid = threadIdx.x;
    int plane = blockIdx.x / 49;            // block covers 1024 pixels; plane = 49 blocks exactly
    int c = plane & 15, b = plane >> 4, d = c & 7;

    const float* tb = ws + TBL + (b * 8 + d) * TSTR + ((c < 8) ? 0 : 448);
    for (int i = tid; i < 448; i += 256) lds[i] = tb[i];
    if (tid == 0) {
        if (c < 8) {
            float mn = ws[2 + (b * 8 + d) * 3 + 0];
            float mx = ws[2 + (b * 8 + d) * 3 + 1];
            float g = mx - mn;
            sc[0] = mn;
            sc[1] = (g < 1e-8f) ? 0.0f : 1.0f / (g + 1e-8f);
            sc[2] = (g < 1e-8f) ? 1.0f : 0.0f;
        } else {
            sc[0] = ws[2 + (b * 8 + d) * 3 + 2];
        }
    }
    __syncthreads();

    int tix = blockIdx.x * 256 + tid;
    int pix0 = tix << 2;
    int ox0 = pix0 % OUT_;                  // multiple of 4 -> 16B-aligned LDS float4
    int oy  = (pix0 / OUT_) % OUT_;

    float4 r;
    if (c < 8) {
        float mn = sc[0], ginv = sc[1];
        bool gdeg = sc[2] != 0.0f;
        float Cr = lds[oy], Sr = lds[OUT_ + oy];
        float4 Cc = *(const float4*)&lds[ox0];
        float4 Sc = *(const float4*)&lds[OUT_ + ox0];
        r.x = gdeg ? 0.0f : ((Cr * Cc.x - Sr * Sc.x) - mn) * ginv;
        r.y = gdeg ? 0.0f : ((Cr * Cc.y - Sr * Sc.y) - mn) * ginv;
        r.z = gdeg ? 0.0f : ((Cr * Cc.z - Sr * Sc.z) - mn) * ginv;
        r.w = gdeg ? 0.0f : ((Cr * Cc.w - Sr * Sc.w) - mn) * ginv;
    } else {
        float thr = sc[0];
        const float scale = (float)L_ / (float)OUT_;
        float fy = (oy + 0.5f) * scale - 0.5f;
        int y0 = (int)fy; float wy = fy - (float)y0;
        float r0 = lds[oy], r1 = lds[OUT_ + oy];
        float4 q0 = *(const float4*)&lds[ox0];
        float4 q1 = *(const float4*)&lds[OUT_ + ox0];
        float qq0[4] = {q0.x, q0.y, q0.z, q0.w};
        float qq1[4] = {q1.x, q1.y, q1.z, q1.w};
        float res[4];
#pragma unroll
        for (int pq = 0; pq < 4; pq++) {
            float fx = (ox0 + pq + 0.5f) * scale - 0.5f;
            int x0i = (int)fx; float wx = fx - (float)x0i;
            float v00 = (fabsf(r0 - qq0[pq]) <= thr) ? 1.0f : 0.0f;
            float v01 = (fabsf(r0 - qq1[pq]) <= thr) ? 1.0f : 0.0f;
            float v10 = (fabsf(r1 - qq0[pq]) <= thr) ? 1.0f : 0.0f;
            float v11 = (fabsf(r1 - qq1[pq]) <= thr) ? 1.0f : 0.0f;
            float top = v00 + wx * (v01 - v00);
            float bot = v10 + wx * (v11 - v10);
            res[pq] = top + wy * (bot - top);
        }
        r = make_float4(res[0], res[1], res[2], res[3]);
    }
    out4[tix] = r;
}

extern "C" void kernel_launch(void* const* d_in, const int* in_sizes, int n_in,
                              void* d_out, int out_size, void* d_ws, size_t ws_size,
                              hipStream_t stream) {
    const float* x = (const float*)d_in[0];
    float* ws = (float*)d_ws;
    unsigned* scratch = (unsigned*)d_out;   // dead before k_out overwrites d_out

    k_pairs<<<NBLK, 256, 0, stream>>>(x, ws, scratch);
    k_collect<<<NBLK, 256, 0, stream>>>(x, ws, scratch);
    k_select<<<NPLANE, 256, 0, stream>>>(ws, scratch);
    k_out<<<NT4 / 256, 256, 0, stream>>>(ws, (float4*)d_out);
}

// Round 5
// 115.886 us; speedup vs baseline: 3.3841x; 1.1356x over previous
//
#include <hip/hip_runtime.h>
#include <cfloat>
#include <math.h>

#define B_ 4
#define L_ 1024
#define D_ 8
#define OUT_ 224
#define NPIX (B_ * 2 * D_ * OUT_ * OUT_)   // 3211264
#define NT4  (NPIX / 4)                    // 802816 = 3136 * 256 exactly
#define TBL 128                            // float offset of per-(b,d) tables in ws
#define TSTR 896                           // per-(b,d): CL[224] SL[224] RV0[224] RV1[224]

#define NPLANE 32
#define PB 16                              // blocks per plane in pair-sweep kernels
#define NBLK (NPLANE * PB)                 // 512
#define NBIN 2048                          // coarse histogram bins
#define SLOTCAP 1024                       // per-block candidate slot (floats)
#define GCAP 8192                          // per-plane candidate cap in LDS
// unordered ranks: ordered k = 1024 + 2*r -> r1=51917 (ordered 104858), r2=51918 (ordered 104859)
#define R1U 51917u
#define R2U 51918u

// scratch layout in d_out (4-byte words); all dead before k_out overwrites d_out.
#define SC_PHIST 0u                                   // NBLK*NBIN partial hists (4 MB)
#define SC_PGAF  ((unsigned)NBLK * (unsigned)NBIN)    // NBLK*2 floats
#define SC_CNT   (SC_PGAF + (unsigned)NBLK * 2u)      // NBLK counts
#define SC_BRK   (SC_CNT + (unsigned)NBLK)            // NPLANE*4 {B1,B2,base,-}
#define SC_SLOT  (SC_BRK + (unsigned)NPLANE * 4u)     // NBLK*SLOTCAP floats (2 MB)

__device__ __forceinline__ float clipnorm(float v, float lo, float inv2, int degen) {
    float xn = degen ? -1.0f : ((v - lo) * inv2 - 1.0f);
    return fminf(fmaxf(xn, -1.0f + 1e-6f), 1.0f - 1e-6f);
}

__device__ __forceinline__ float sort64(float val, int tid) {
#pragma unroll
    for (int k = 2; k <= 64; k <<= 1) {
        bool up = ((tid & k) == 0);
#pragma unroll
        for (int j = k >> 1; j > 0; j >>= 1) {
            float o = __shfl_xor(val, j);
            bool lower = ((tid & j) == 0);
            float mn = fminf(val, o), mx = fmaxf(val, o);
            val = (lower == up) ? mn : mx;
        }
    }
    return val;
}

// ---------------------------------------------------------------------------
// K0: global min/max of x, computed ONCE (x = 128 KB). 1 block x 1024 threads.
// ---------------------------------------------------------------------------
__global__ __launch_bounds__(1024) void k_minmax(const float* __restrict__ x,
                                                 float* __restrict__ ws) {
    __shared__ float red[32];
    const int tid  = threadIdx.x;
    const int lane = tid & 63;
    const int wave = tid >> 6;

    float lo = FLT_MAX, hi = -FLT_MAX;
    const float4* x4 = (const float4*)x;
    for (int i = tid; i < (B_ * L_ * D_) / 4; i += 1024) {
        float4 q = x4[i];
        lo = fminf(fminf(fminf(lo, q.x), q.y), fminf(q.z, q.w));
        hi = fmaxf(fmaxf(fmaxf(hi, q.x), q.y), fmaxf(q.z, q.w));
    }
#pragma unroll
    for (int off = 32; off; off >>= 1) {
        lo = fminf(lo, __shfl_down(lo, off));
        hi = fmaxf(hi, __shfl_down(hi, off));
    }
    if (lane == 0) { red[wave] = lo; red[16 + wave] = hi; }
    __syncthreads();
    if (wave == 0 && lane < 16) {
        float l2 = red[lane], h2 = red[16 + lane];
#pragma unroll
        for (int off = 8; off; off >>= 1) {
            l2 = fminf(l2, __shfl_down(l2, off));
            h2 = fmaxf(h2, __shfl_down(h2, off));
        }
        if (lane == 0) { ws[0] = l2; ws[1] = h2; }
    }
}

// ---------------------------------------------------------------------------
// K1: pair sweep via cyclic-offset decomposition -> partial hist + GAF
// partials + axis tables. 512 blocks x 256 threads. Block bip of plane p owns
// offsets o in [bip*32+1, bip*32+32]; pair (j, (j+o)&1023) hits each unordered
// pair exactly once (o=512: j<512 only). No predication waste.
// ---------------------------------------------------------------------------
__global__ __launch_bounds__(256) void k_pairs(const float* __restrict__ x,
                                               const float* __restrict__ ws,
                                               float* __restrict__ wsw,
                                               unsigned* __restrict__ scratch) {
    __shared__ __align__(16) float4 S4[L_];   // (s, cc, ssn, 0) 16 KB
    __shared__ unsigned hist[NBIN];           // 8 KB
    __shared__ float red[16];

    const int tid  = threadIdx.x;
    const int lane = tid & 63;
    const int wave = tid >> 6;
    const int bid  = blockIdx.x;
    const int p    = bid >> 4;        // plane 0..31
    const int bip  = bid & 15;        // block-in-plane 0..15
    const int b    = p >> 3, d = p & 7;

    const float glo = ws[0], ghi = ws[1];
    const float rng   = ghi - glo;
    const int   degen = rng < 1e-8f;
    const float inv2  = 2.0f / (rng + 1e-8f);
    const float scale = (float)(NBIN - 1) / fmaxf(rng, 1e-20f);

    // stage series + cos/sin packed; zero hist
    for (int i = tid; i < L_; i += 256) {
        float v = x[(b * L_ + i) * D_ + d];
        float c = clipnorm(v, glo, inv2, degen);
        S4[i] = make_float4(v, c, sqrtf(fmaxf(0.0f, 1.0f - c * c)), 0.0f);
    }
    for (int i = tid; i < NBIN; i += 256) hist[i] = 0u;
    __syncthreads();

    // register-cached columns: j = tid, tid+256, tid+512, tid+768
    float4 col[4];
#pragma unroll
    for (int q = 0; q < 4; q++) col[q] = S4[tid + q * 256];

    float gmn = FLT_MAX, gmx = -FLT_MAX;
#pragma unroll
    for (int q = 0; q < 4; q++) {             // diagonal GAF terms
        float g = col[q].y * col[q].y - col[q].z * col[q].z;
        gmn = fminf(gmn, g); gmx = fmaxf(gmx, g);
    }

    const int obase = bip * 32;
    for (int oo = 1; oo <= 32; ++oo) {
        const int o = obase + oo;             // 1..512
        const int nq = (o == 512) ? 2 : 4;    // o=512: each pair once (j<512)
#pragma unroll
        for (int q = 0; q < 4; q++) {
            if (q < nq) {
                int jp = (tid + q * 256 + o) & 1023;
                float4 P = S4[jp];            // ds_read_b128, stride-1 lanes
                float dd = fabsf(col[q].x - P.x);
                int bin = min((int)(dd * scale), NBIN - 1);
                atomicAdd(&hist[bin], 1u);
                float g = col[q].y * P.y - col[q].z * P.z;
                gmn = fminf(gmn, g); gmx = fmaxf(gmx, g);
            }
        }
    }
    __syncthreads();

    // flush partial hist (coalesced)
    {
        unsigned* ph = scratch + SC_PHIST + (unsigned)bid * NBIN;
        for (int i = tid; i < NBIN; i += 256) ph[i] = hist[i];
    }
    // GAF partials -> scratch
#pragma unroll
    for (int off = 32; off; off >>= 1) {
        gmn = fminf(gmn, __shfl_down(gmn, off));
        gmx = fmaxf(gmx, __shfl_down(gmx, off));
    }
    if (lane == 0) { red[wave] = gmn; red[8 + wave] = gmx; }
    __syncthreads();
    if (tid == 0) {
        float* pg = (float*)scratch + SC_PGAF + bid * 2;
        pg[0] = fminf(fminf(red[0], red[1]), fminf(red[2], red[3]));
        pg[1] = fmaxf(fmaxf(red[8], red[9]), fmaxf(red[10], red[11]));
    }
    // axis tables for k_out (one block per plane)
    if (bip == 0) {
        const float scL = (float)L_ / (float)OUT_;
        float* basep = wsw + TBL + p * TSTR;
        for (int o = tid; o < OUT_; o += 256) {
            float fx = (o + 0.5f) * scL - 0.5f;
            int x0 = (int)fx; float wx = fx - (float)x0;
            float q0 = x[(b * L_ + x0) * D_ + d];
            float q1 = x[(b * L_ + x0 + 1) * D_ + d];
            float c0 = clipnorm(q0, glo, inv2, degen), c1 = clipnorm(q1, glo, inv2, degen);
            float s0 = sqrtf(fmaxf(0.0f, 1.0f - c0 * c0)), s1 = sqrtf(fmaxf(0.0f, 1.0f - c1 * c1));
            basep[o]        = c0 + wx * (c1 - c0);   // CL
            basep[OUT_ + o] = s0 + wx * (s1 - s0);   // SL
            basep[448 + o]  = q0;                    // RV0
            basep[672 + o]  = q1;                    // RV1
        }
    }
}

// ---------------------------------------------------------------------------
// K2: reduce each plane's 16 partial hists ONCE -> bracket {B1,B2,base} to
// scratch; also finalize GAF min/max -> ws. 32 blocks x 256 threads.
// ---------------------------------------------------------------------------
__global__ __launch_bounds__(256) void k_bracket(float* __restrict__ ws,
                                                 unsigned* __restrict__ scratch) {
    __shared__ unsigned wsum[4];
    __shared__ unsigned sB1, sB2, sBase;

    const int tid  = threadIdx.x;
    const int lane = tid & 63;
    const int wave = tid >> 6;
    const int p    = blockIdx.x;

    // thread owns bins [8t, 8t+8)
    unsigned loc[8];
#pragma unroll
    for (int q = 0; q < 8; q++) loc[q] = 0u;
    const unsigned* ph = scratch + SC_PHIST + (unsigned)(p * PB) * NBIN;
    for (int k = 0; k < PB; k++) {
        const uint4* ph4 = (const uint4*)(ph + (unsigned)k * NBIN) + tid * 2;
        uint4 a = ph4[0], c4 = ph4[1];
        loc[0] += a.x; loc[1] += a.y; loc[2] += a.z; loc[3] += a.w;
        loc[4] += c4.x; loc[5] += c4.y; loc[6] += c4.z; loc[7] += c4.w;
    }
    unsigned tsum = 0u;
#pragma unroll
    for (int q = 0; q < 8; q++) tsum += loc[q];
    unsigned inc = tsum;
#pragma unroll
    for (int off = 1; off < 64; off <<= 1) {
        unsigned o = __shfl_up(inc, off);
        if (lane >= off) inc += o;
    }
    if (lane == 63) wsum[wave] = inc;
    __syncthreads();
    unsigned woff = 0u;
    for (int w2 = 0; w2 < 4; w2++) woff += (w2 < wave) ? wsum[w2] : 0u;
    unsigned run = woff + inc - tsum;
#pragma unroll
    for (int q = 0; q < 8; q++) {
        unsigned prev = run; run += loc[q];
        if (prev < R1U && run >= R1U) { sB1 = (unsigned)(tid * 8 + q); sBase = prev; }
        if (prev < R2U && run >= R2U) { sB2 = (unsigned)(tid * 8 + q); }
    }
    __syncthreads();
    if (tid == 0) {
        unsigned* brk = scratch + SC_BRK + (unsigned)p * 4u;
        brk[0] = sB1; brk[1] = sB2; brk[2] = sBase;
    }
    // finalize GAF min/max
    if (tid < 16) {
        const float* pg = (const float*)scratch + SC_PGAF + (unsigned)(p * PB + tid) * 2u;
        float mn = pg[0], mx = pg[1];
#pragma unroll
        for (int off = 8; off; off >>= 1) {
            mn = fminf(mn, __shfl_down(mn, off));
            mx = fmaxf(mx, __shfl_down(mx, off));
        }
        if (tid == 0) {
            ws[2 + p * 3 + 0] = mn;
            ws[2 + p * 3 + 1] = mx;
        }
    }
}

// ---------------------------------------------------------------------------
// K3: candidate collect (offset decomposition, reads 3-word bracket).
// 512 blocks x 256 threads, private per-block slots, no global atomics.
// ---------------------------------------------------------------------------
__global__ __launch_bounds__(256) void k_collect(const float* __restrict__ x,
                                                 const float* __restrict__ ws,
                                                 unsigned* __restrict__ scratch) {
    __shared__ float s[L_];
    __shared__ float stage[SLOTCAP];
    __shared__ unsigned scnt;

    const int tid  = threadIdx.x;
    const int bid  = blockIdx.x;
    const int p    = bid >> 4;
    const int bip  = bid & 15;
    const int b    = p >> 3, d = p & 7;

    const float glo = ws[0], ghi = ws[1];
    const float scale = (float)(NBIN - 1) / fmaxf(ghi - glo, 1e-20f);

    const unsigned* brk = scratch + SC_BRK + (unsigned)p * 4u;
    const unsigned B1 = brk[0], B2 = brk[1];
    // float filter identical to int binning: floor(y)>=B1 <=> y>=B1; floor(y)<=B2 <=> y<B2+1
    const float fB1   = (float)B1;
    const float fB2p1 = (B2 >= (unsigned)(NBIN - 1)) ? FLT_MAX : (float)(B2 + 1u);

    for (int i = tid; i < L_; i += 256) s[i] = x[(b * L_ + i) * D_ + d];
    if (tid == 0) scnt = 0u;
    __syncthreads();

    float sj[4];
#pragma unroll
    for (int q = 0; q < 4; q++) sj[q] = s[tid + q * 256];

    const int obase = bip * 32;
    for (int oo = 1; oo <= 32; ++oo) {
        const int o = obase + oo;
        const int nq = (o == 512) ? 2 : 4;
#pragma unroll
        for (int q = 0; q < 4; q++) {
            if (q < nq) {
                int jp = (tid + q * 256 + o) & 1023;
                float dd = fabsf(sj[q] - s[jp]);
                float y = dd * scale;
                if (y >= fB1 && y < fB2p1) {
                    unsigned idx = atomicAdd(&scnt, 1u);
                    if (idx < (unsigned)SLOTCAP) stage[idx] = dd;
                }
            }
        }
    }
    __syncthreads();
    {
        unsigned bc = scnt; bc = (bc < (unsigned)SLOTCAP) ? bc : (unsigned)SLOTCAP;
        float* slot = (float*)scratch + SC_SLOT + (unsigned)bid * SLOTCAP;
        for (unsigned idx = tid; idx < bc; idx += 256) slot[idx] = stage[idx];
        if (tid == 0) scratch[SC_CNT + bid] = bc;
    }
}

// ---------------------------------------------------------------------------
// K4: per plane, gather candidates + exact selection of ranks r1/r1+1 ->
// thr. 32 blocks x 256 threads. (R4-verified selection core.)
// ---------------------------------------------------------------------------
__global__ __launch_bounds__(256) void k_select(float* __restrict__ ws,
                                                const unsigned* __restrict__ scratch) {
    __shared__ float cand[GCAP];       // 32 KB
    __shared__ float nbuf[2048];       // 8 KB
    __shared__ unsigned h2[1024];      // 4 KB
    __shared__ unsigned wsum[4];
    __shared__ unsigned scnt, sT1, sT2, sC1, sH1, uminb, umaxb;
    __shared__ float sv1, sv2;
    __shared__ unsigned cpre[17];

    const int tid  = threadIdx.x;
    const int lane = tid & 63;
    const int wave = tid >> 6;
    const int p    = blockIdx.x;

    const float glo = ws[0], ghi = ws[1];
    const float scale = (float)(NBIN - 1) / fmaxf(ghi - glo, 1e-20f);

    const unsigned* brk = scratch + SC_BRK + (unsigned)p * 4u;
    const unsigned B1 = brk[0], B2 = brk[1], base = brk[2];

    // parallel prefix of the plane's 16 slot counts (wave 0)
    if (wave == 0) {
        unsigned c = (lane < PB) ? scratch[SC_CNT + (unsigned)(p * PB + lane)] : 0u;
        unsigned incc = c;
#pragma unroll
        for (int off = 1; off < 16; off <<= 1) {
            unsigned o = __shfl_up(incc, off);
            if ((lane & 15) >= off) incc += o;
        }
        if (lane < PB) { cpre[lane] = incc - c; if (lane == PB - 1) cpre[16] = incc; }
    }
    __syncthreads();

    unsigned n = cpre[16]; n = (n < (unsigned)GCAP) ? n : (unsigned)GCAP;
    for (int k = 0; k < PB; k++) {
        unsigned off = cpre[k];
        unsigned ck  = ((k + 1 < PB) ? cpre[k + 1] : cpre[16]) - cpre[k];
        const float* slot = (const float*)scratch + SC_SLOT + (unsigned)(p * PB + k) * SLOTCAP;
        for (unsigned idx = tid; idx < ck; idx += 256) {
            unsigned dst = off + idx;
            if (dst < (unsigned)GCAP) cand[dst] = slot[idx];
        }
    }
    __syncthreads();

    float* cur = cand;
    float* nxt = nbuf;
    unsigned ncur = n;
    unsigned r1 = R1U - base;             // 1-indexed rank within candidates
    float vlo = (float)B1 / scale;
    float vhi = (float)(B2 + 1u) / scale;
    float v1 = 0.0f, v2 = 0.0f;
    bool done = false;

    for (int it = 0; it < 6 && !done; ++it) {
        if (tid == 0) scnt = 0u;
#pragma unroll
        for (int q = 0; q < 4; q++) h2[tid + q * 256] = 0u;
        __syncthreads();

        if (ncur <= 64u) {
            if (tid < 64) {
                float val = ((unsigned)tid < ncur) ? cur[tid] : FLT_MAX;
                val = sort64(val, tid);
                float v1l = __shfl(val, (int)r1 - 1);
                float v2l = __shfl(val, (int)r1);
                if (tid == 0) { sv1 = v1l; sv2 = v2l; }
            }
            __syncthreads();
            v1 = sv1; v2 = sv2;
            done = true;
            break;
        }

        float sc2 = 1023.0f / fmaxf(vhi - vlo, 1e-30f);
        for (unsigned k = tid; k < ncur; k += 256) {
            int bb = (int)((cur[k] - vlo) * sc2);
            bb = max(0, min(bb, 1023));
            atomicAdd(&h2[bb], 1u);
        }
        __syncthreads();

        // scan 1024 bins with 256 threads: thread owns h2[4t..4t+4)
        unsigned l[4];
#pragma unroll
        for (int q = 0; q < 4; q++) l[q] = h2[4 * tid + q];
        unsigned tsum = l[0] + l[1] + l[2] + l[3];
        unsigned inc = tsum;
#pragma unroll
        for (int off = 1; off < 64; off <<= 1) {
            unsigned o = __shfl_up(inc, off);
            if (lane >= off) inc += o;
        }
        if (lane == 63) wsum[wave] = inc;
        __syncthreads();
        unsigned woff = 0u;
        for (int w2 = 0; w2 < 4; w2++) woff += (w2 < wave) ? wsum[w2] : 0u;
        unsigned prev = woff + inc - tsum;
#pragma unroll
        for (int q = 0; q < 4; q++) {
            unsigned nrun = prev + l[q];
            if (prev < r1 && nrun >= r1) { sT1 = 4u * tid + q; sC1 = prev; sH1 = l[q]; }
            if (prev < r1 + 1u && nrun >= r1 + 1u) { sT2 = 4u * tid + q; }
            prev = nrun;
        }
        __syncthreads();
        const unsigned t1 = sT1, t2 = sT2, c1 = sC1, h1 = sH1;

        if (t1 != t2) {
            if (tid == 0) { uminb = 0xFFFFFFFFu; umaxb = 0u; }
            __syncthreads();
            for (unsigned k = tid; k < ncur; k += 256) {
                float val = cur[k];
                int bb = (int)((val - vlo) * sc2);
                bb = max(0, min(bb, 1023));
                if (bb == (int)t1) atomicMax(&umaxb, __float_as_uint(val));
                else if (bb > (int)t1) atomicMin(&uminb, __float_as_uint(val));
            }
            __syncthreads();
            v1 = __uint_as_float(umaxb);
            v2 = __uint_as_float(uminb);
            done = true;
            break;
        }

        if (h1 <= 64u) {
            for (unsigned k = tid; k < ncur; k += 256) {
                float val = cur[k];
                int bb = (int)((val - vlo) * sc2);
                bb = max(0, min(bb, 1023));
                if (bb == (int)t1) {
                    unsigned idx = atomicAdd(&scnt, 1u);
                    if (idx < 64u) nxt[idx] = val;
                }
            }
            __syncthreads();
            unsigned cnt = (scnt < 64u) ? scnt : 64u;
            unsigned rr = r1 - c1;
            if (tid < 64) {
                float val = ((unsigned)tid < cnt) ? nxt[tid] : FLT_MAX;
                val = sort64(val, tid);
                float v1l = __shfl(val, (int)rr - 1);
                float v2l = __shfl(val, (int)rr);
                if (tid == 0) { sv1 = v1l; sv2 = v2l; }
            }
            __syncthreads();
            v1 = sv1; v2 = sv2;
            done = true;
            break;
        }

        // big bin: compact and refine
        for (unsigned k = tid; k < ncur; k += 256) {
            float val = cur[k];
            int bb = (int)((val - vlo) * sc2);
            bb = max(0, min(bb, 1023));
            if (bb == (int)t1) {
                unsigned idx = atomicAdd(&scnt, 1u);
                if (idx < 2048u) nxt[idx] = val;
            }
        }
        __syncthreads();
        ncur = (scnt < 2048u) ? scnt : 2048u;
        r1 = r1 - c1;
        float nvlo = vlo + (float)t1 / sc2;
        float nvhi = vlo + (float)(t1 + 1u) / sc2;
        vlo = nvlo; vhi = nvhi;
        float* tmp = cur; cur = nxt; nxt = tmp;
        __syncthreads();
    }
    if (!done) { v1 = vlo; v2 = vhi; }    // pathological ties fallback

    if (tid == 0) ws[2 + p * 3 + 2] = v1 + (v2 - v1) * 0.5f;
}

// ---------------------------------------------------------------------------
// K5: output kernel — verbatim green. Overwrites all of d_out (incl. scratch).
// ---------------------------------------------------------------------------
__global__ __launch_bounds__(256) void k_out(const float* __restrict__ ws,
                                             float4* __restrict__ out4) {
    __shared__ __align__(16) float lds[448];
    __shared__ float sc[3];

    const int tid = threadIdx.x;
    int plane = blockIdx.x / 49;            // block covers 1024 pixels; plane = 49 blocks exactly
    int c = plane & 15, b = plane >> 4, d = c & 7;

    const float* tb = ws + TBL + (b * 8 + d) * TSTR + ((c < 8) ? 0 : 448);
    for (int i = tid; i < 448; i += 256) lds[i] = tb[i];
    if (tid == 0) {
        if (c < 8) {
            float mn = ws[2 + (b * 8 + d) * 3 + 0];
            float mx = ws[2 + (b * 8 + d) * 3 + 1];
            float g = mx - mn;
            sc[0] = mn;
            sc[1] = (g < 1e-8f) ? 0.0f : 1.0f / (g + 1e-8f);
            sc[2] = (g < 1e-8f) ? 1.0f : 0.0f;
        } else {
            sc[0] = ws[2 + (b * 8 + d) * 3 + 2];
        }
    }
    __syncthreads();

    int tix = blockIdx.x * 256 + tid;
    int pix0 = tix << 2;
    int ox0 = pix0 % OUT_;                  // multiple of 4 -> 16B-aligned LDS float4
    int oy  = (pix0 / OUT_) % OUT_;

    float4 r;
    if (c < 8) {
        float mn = sc[0], ginv = sc[1];
        bool gdeg = sc[2] != 0.0f;
        float Cr = lds[oy], Sr = lds[OUT_ + oy];
        float4 Cc = *(const float4*)&lds[ox0];
        float4 Sc = *(const float4*)&lds[OUT_ + ox0];
        r.x = gdeg ? 0.0f : ((Cr * Cc.x - Sr * Sc.x) - mn) * ginv;
        r.y = gdeg ? 0.0f : ((Cr * Cc.y - Sr * Sc.y) - mn) * ginv;
        r.z = gdeg ? 0.0f : ((Cr * Cc.z - Sr * Sc.z) - mn) * ginv;
        r.w = gdeg ? 0.0f : ((Cr * Cc.w - Sr * Sc.w) - mn) * ginv;
    } else {
        float thr = sc[0];
        const float scale = (float)L_ / (float)OUT_;
        float fy = (oy + 0.5f) * scale - 0.5f;
        int y0 = (int)fy; float wy = fy - (float)y0;
        float r0 = lds[oy], r1 = lds[OUT_ + oy];
        float4 q0 = *(const float4*)&lds[ox0];
        float4 q1 = *(const float4*)&lds[OUT_ + ox0];
        float qq0[4] = {q0.x, q0.y, q0.z, q0.w};
        float qq1[4] = {q1.x, q1.y, q1.z, q1.w};
        float res[4];
#pragma unroll
        for (int pq = 0; pq < 4; pq++) {
            float fx = (ox0 + pq + 0.5f) * scale - 0.5f;
            int x0i = (int)fx; float wx = fx - (float)x0i;
            float v00 = (fabsf(r0 - qq0[pq]) <= thr) ? 1.0f : 0.0f;
            float v01 = (fabsf(r0 - qq1[pq]) <= thr) ? 1.0f : 0.0f;
            float v10 = (fabsf(r1 - qq0[pq]) <= thr) ? 1.0f : 0.0f;
            float v11 = (fabsf(r1 - qq1[pq]) <= thr) ? 1.0f : 0.0f;
            float top = v00 + wx * (v01 - v00);
            float bot = v10 + wx * (v11 - v10);
            res[pq] = top + wy * (bot - top);
        }
        r = make_float4(res[0], res[1], res[2], res[3]);
    }
    out4[tix] = r;
}

extern "C" void kernel_launch(void* const* d_in, const int* in_sizes, int n_in,
                              void* d_out, int out_size, void* d_ws, size_t ws_size,
                              hipStream_t stream) {
    const float* x = (const float*)d_in[0];
    float* ws = (float*)d_ws;
    unsigned* scratch = (unsigned*)d_out;   // dead before k_out overwrites d_out

    k_minmax<<<1, 1024, 0, stream>>>(x, ws);
    k_pairs<<<NBLK, 256, 0, stream>>>(x, ws, ws, scratch);
    k_bracket<<<NPLANE, 256, 0, stream>>>(ws, scratch);
    k_collect<<<NBLK, 256, 0, stream>>>(x, ws, scratch);
    k_select<<<NPLANE, 256, 0, stream>>>(ws, scratch);
    k_out<<<NT4 / 256, 256, 0, stream>>>(ws, (float4*)d_out);
}